// Round 8
// baseline (277.020 us; speedup 1.0000x reference)
//
#include <hip/hip_runtime.h>
#include <hip/hip_bf16.h>
#include <stdint.h>

typedef __bf16 bf16_t;
typedef __bf16 bf16x8 __attribute__((ext_vector_type(8)));
typedef float f32x4 __attribute__((ext_vector_type(4)));

#define NB      4
#define T_TXT   2048
#define T_IMG   8
#define N_LAT   64
#define DIM     2048
#define DIM_VIS 1024
#define HEADS   8
#define DHEAD   64
#define INNER   512

__device__ __forceinline__ void gld_lds16(const void* g, void* l) {
    __builtin_amdgcn_global_load_lds((const __attribute__((address_space(1))) void*)g,
                                     (__attribute__((address_space(3))) void*)l,
                                     16, 0, 0);
}

// ---------- fused preamble: 3 weight transposes + media cvt + cumsum ----------
// grid = 4100: [0,3072) transpose tiles (1024 per matrix), [3072,4096) cvt,
// [4096,4100) cumsum-bucket. One dispatch instead of three. No extra ws.
__global__ __launch_bounds__(256) void prep_k(const float* __restrict__ Wq,
                                              const float* __restrict__ Wkv,
                                              const float* __restrict__ Wout,
                                              bf16_t* __restrict__ WqT,
                                              bf16_t* __restrict__ WkvT,
                                              bf16_t* __restrict__ WoutT,
                                              const float* __restrict__ media,
                                              bf16_t* __restrict__ mediab,
                                              const void* __restrict__ locs,
                                              int* __restrict__ bstart,
                                              int* __restrict__ bcnt) {
    __shared__ union {
        float tile[32][33];
        struct { int so[4]; int sf[4]; int sc[256]; int sstart[T_IMG]; } cs;
    } sm;
    int bid = blockIdx.x;
    int tid = threadIdx.x;

    if (bid < 3072) {               // ---- transpose+cvt of one 32x32 tile ----
        int which = bid >> 10, tix = bid & 1023;
        const float* in; bf16_t* out; int R, C;
        if (which == 0)      { in = Wq;   out = WqT;   R = 2048; C = 512;  }
        else if (which == 1) { in = Wkv;  out = WkvT;  R = 1024; C = 1024; }
        else                 { in = Wout; out = WoutT; R = 512;  C = 2048; }
        int nbx = C >> 5;
        int bx = tix % nbx, by = tix / nbx;
        int c0 = bx * 32, r0 = by * 32;
        int x = tid & 31, y = tid >> 5;    // 32 x 8
#pragma unroll
        for (int d = 0; d < 4; d++)
            sm.tile[y + d * 8][x] = in[(size_t)(r0 + y + d * 8) * C + c0 + x];
        __syncthreads();
#pragma unroll
        for (int d = 0; d < 4; d++)
            out[(size_t)(c0 + y + d * 8) * R + r0 + x] = (bf16_t)sm.tile[x][y + d * 8];
        return;
    }
    if (bid < 4096) {               // ---- media fp32 -> bf16 ----
        int idx = ((bid - 3072) * 256 + tid) * 8;
        f32x4 a = *(const f32x4*)(media + idx);
        f32x4 b = *(const f32x4*)(media + idx + 4);
        bf16x8 o;
#pragma unroll
        for (int i = 0; i < 4; i++) { o[i] = (bf16_t)a[i]; o[i + 4] = (bf16_t)b[i]; }
        *(bf16x8*)(mediab + idx) = o;
        return;
    }
    // ---- cumsum + contiguous bucket ranges (NO atomics), b = bid-4096 -------
    {
        int b = bid - 4096, t = tid;
        const unsigned* up = (const unsigned*)locs;
        const int* ip = (const int*)locs;
        const unsigned char* bp = (const unsigned char*)locs;
        const float* fp = (const float*)locs;

        int other = 0, nf = 0;
#pragma unroll
        for (int i = 0; i < 8; i++) {
            unsigned wv = up[t * 8 + i];
            nf    += (wv == 0x3F800000u);
            other += (wv != 0u && wv != 1u && wv != 0x3F800000u);
        }
#pragma unroll
        for (int off = 32; off > 0; off >>= 1) { other += __shfl_xor(other, off); nf += __shfl_xor(nf, off); }
        int wid = t >> 6, lane = t & 63;
        if (lane == 0) { sm.cs.so[wid] = other; sm.cs.sf[wid] = nf; }
        __syncthreads();
        other = sm.cs.so[0] + sm.cs.so[1] + sm.cs.so[2] + sm.cs.so[3];
        nf    = sm.cs.sf[0] + sm.cs.sf[1] + sm.cs.sf[2] + sm.cs.sf[3];
        int mode = (other > 0) ? 0 : ((nf > 0) ? 2 : 1);   // 0=u8, 1=i32, 2=f32

        int v[8];
        int s = 0;
#pragma unroll
        for (int i = 0; i < 8; i++) {
            int idx = b * T_TXT + t * 8 + i;
            int xv;
            if (mode == 1)      xv = ip[idx];
            else if (mode == 0) xv = (int)bp[idx];
            else                xv = (fp[idx] != 0.f) ? 1 : 0;
            v[i] = xv;
            s += xv;
        }
        if (t < T_IMG) sm.cs.sstart[t] = T_TXT;   // sentinel
        sm.cs.sc[t] = s;
        __syncthreads();
        for (int off = 1; off < 256; off <<= 1) {
            int add = (t >= off) ? sm.cs.sc[t - off] : 0;
            __syncthreads();
            sm.cs.sc[t] += add;
            __syncthreads();
        }
        int run = sm.cs.sc[t] - s;   // exclusive prefix of this thread's chunk
#pragma unroll
        for (int i = 0; i < 8; i++) {
            run += v[i];
            if (v[i] && run <= T_IMG) sm.cs.sstart[run - 1] = t * 8 + i;  // unique writer
        }
        __syncthreads();
        if (t < T_IMG) {
            int st = sm.cs.sstart[t];
            int nx = (t + 1 < T_IMG) ? sm.cs.sstart[t + 1] : T_TXT;
            bstart[b * T_IMG + t] = st;
            bcnt[b * T_IMG + t]   = nx - st;   // 0 for empty tail buckets
        }
    }
}

// ---------- LayerNorm: fp32 in, bf16 out; one block per row of 2048 -----------
__global__ __launch_bounds__(256) void ln_k(const float* __restrict__ x,
                                            const float* __restrict__ gamma,
                                            const float* __restrict__ beta,
                                            bf16_t* __restrict__ xn) {
    int row = blockIdx.x;
    int t = threadIdx.x;
    const float* xp = x + (size_t)row * DIM + t * 8;
    f32x4 v0 = *(const f32x4*)xp;
    f32x4 v1 = *(const f32x4*)(xp + 4);
    float f[8];
    float s = 0.f, ss = 0.f;
#pragma unroll
    for (int i = 0; i < 4; i++) { f[i] = v0[i]; f[i + 4] = v1[i]; }
#pragma unroll
    for (int i = 0; i < 8; i++) { s += f[i]; ss += f[i] * f[i]; }
#pragma unroll
    for (int off = 32; off > 0; off >>= 1) { s += __shfl_xor(s, off); ss += __shfl_xor(ss, off); }
    __shared__ float sbuf[4], sbuf2[4];
    int wid = t >> 6, lane = t & 63;
    if (lane == 0) { sbuf[wid] = s; sbuf2[wid] = ss; }
    __syncthreads();
    s  = sbuf[0] + sbuf[1] + sbuf[2] + sbuf[3];
    ss = sbuf2[0] + sbuf2[1] + sbuf2[2] + sbuf2[3];
    float mu  = s * (1.0f / DIM);
    float var = ss * (1.0f / DIM) - mu * mu;
    float rs  = rsqrtf(var + 1e-5f);
    f32x4 g0 = *(const f32x4*)(gamma + t * 8);
    f32x4 g1 = *(const f32x4*)(gamma + t * 8 + 4);
    f32x4 b0 = *(const f32x4*)(beta + t * 8);
    f32x4 b1 = *(const f32x4*)(beta + t * 8 + 4);
    bf16x8 o;
#pragma unroll
    for (int i = 0; i < 4; i++) {
        o[i]     = (bf16_t)((f[i]     - mu) * rs * g0[i] + b0[i]);
        o[i + 4] = (bf16_t)((f[i + 4] - mu) * rs * g1[i] + b1[i]);
    }
    *(bf16x8*)(xn + (size_t)row * DIM + t * 8) = o;
}

// ---------- GEMM body: 256x256 tile, 8 waves, BK=64, A-in-LDS / B-from-L2 -----
// R6 theory (untested due to R7 infra fail): binding resource is LDS traffic.
// Old structure moved 256KB/CU through LDS per K-tile (A read 4x-duplicated,
// B 2x) vs 621cyc of MFMA -> MfmaUtil capped ~16%. Fix: B (<=2MB L2-resident
// weight panel) loaded as fragments DIRECTLY from global into registers
// (8x b128/wave/tile, exactly the bytes the MFMAs need). LDS carries only A:
// per-tile traffic -37%, gld_lds staging halved; B rides VMEM/L2 concurrently
// with A's LDS path. B-loads issue BEFORE the A-stage so the __syncthreads
// vmcnt(0) drain covers B too (it's older). Proven 2-phase barrier loop (R4).
// LDS: 2 bufs x 32KB (A only) = 64KB. Chunk-major 16x32 sections (0 conflicts).
template <typename OT>
__device__ __forceinline__ void gemm_body256(const bf16_t* __restrict__ A,
                                             const bf16_t* __restrict__ Bt,
                                             OT* __restrict__ C,
                                             int M, int N, int K, int Kper,
                                             float scale, int bid,
                                             int gx, int gy, int gz,
                                             bf16_t* lA) {
    int tid = threadIdx.x;
    int w = tid >> 6, lane = tid & 63;
    int wm = w >> 2, wn = w & 3;

    // bijective XCD swizzle (nwg % 8 == 0 for all dispatches)
    int nwg = gx * gy * gz;
    int cpx = nwg >> 3;
    int nid = (bid & 7) * cpx + (bid >> 3);
    int tpy = gx * gz;
    int by = nid / tpy;
    int rr = nid - by * tpy;
    int bz = rr / gx;
    int bx = rr - bz * gx;

    int bm0 = by * 256, bn0 = bx * 256;
    int kbase = bz * Kper;
    int q = lane >> 4, l16 = lane & 15;
    int rbase = q * 128 + l16 * 8;   // intra-section fragment offset (elems)

    // A staging: wave w owns 16-row groups {2w, 2w+1}; section = 16r x 32k,
    // chunk-major: lane(q,l16) -> (row=l16, k-chunk=q)
    const bf16_t* sA0 = A + (size_t)(bm0 + (2 * w) * 16     + l16) * K + kbase + q * 8;
    const bf16_t* sA1 = A + (size_t)(bm0 + (2 * w + 1) * 16 + l16) * K + kbase + q * 8;
    // B fragment pointers: lane(q,l16) reads Bt[bn0+wn*64+nt*16+l16][.. + q*8]
    const bf16_t* pB[4];
#pragma unroll
    for (int nt = 0; nt < 4; nt++)
        pB[nt] = Bt + (size_t)(bn0 + wn * 64 + nt * 16 + l16) * K + kbase + q * 8;

    f32x4 acc[8][4];
#pragma unroll
    for (int i = 0; i < 8; i++)
#pragma unroll
        for (int j = 0; j < 4; j++)
            acc[i][j] = (f32x4){0.f, 0.f, 0.f, 0.f};

    auto stageA = [&](int buf, int t) {
        int off = t * 64;
        bf16_t* d = lA + buf * 16384;
        gld_lds16(sA0 + off,      d + (2 * w) * 512);          // kh=0
        gld_lds16(sA1 + off,      d + (2 * w + 1) * 512);
        gld_lds16(sA0 + off + 32, d + (16 + 2 * w) * 512);     // kh=1
        gld_lds16(sA1 + off + 32, d + (16 + 2 * w + 1) * 512);
    };

    int T = Kper >> 6;   // K-tiles of 64 (>= 4 for all dispatches)
    stageA(0, 0);
    __syncthreads();

    for (int t = 0; t < T; ++t) {
        int buf = t & 1;
        const bf16_t* LA = lA + buf * 16384;

        // B fragments for tile t: issue FIRST (older than A-stage in vmcnt order)
        bf16x8 bq[8];
#pragma unroll
        for (int ks = 0; ks < 2; ks++)
#pragma unroll
            for (int nt = 0; nt < 4; nt++)
                bq[ks * 4 + nt] = *(const bf16x8*)(pB[nt] + t * 64 + ks * 32);

        if (t + 1 < T) stageA(buf ^ 1, t + 1);

#pragma unroll
        for (int ks = 0; ks < 2; ks++) {
#pragma unroll
            for (int mt = 0; mt < 8; mt++) {
                bf16x8 af = *(const bf16x8*)(LA + (ks * 16 + wm * 8 + mt) * 512 + rbase);
#pragma unroll
                for (int nt = 0; nt < 4; nt++)
                    acc[mt][nt] = __builtin_amdgcn_mfma_f32_16x16x32_bf16(af, bq[ks * 4 + nt], acc[mt][nt], 0, 0, 0);
            }
        }
        __syncthreads();   // A(t+1) landed; all waves done with buf
    }

    OT* Cz = C + (size_t)bz * M * N;
#pragma unroll
    for (int mt = 0; mt < 8; mt++)
#pragma unroll
        for (int nt = 0; nt < 4; nt++)
#pragma unroll
            for (int r = 0; r < 4; r++) {
                int row = bm0 + wm * 128 + mt * 16 + q * 4 + r;
                int col = bn0 + wn * 64 + nt * 16 + l16;
                Cz[(size_t)row * N + col] = (OT)(acc[mt][nt][r] * scale);
            }
}

// ---------- merged GEMM1 + GEMM2 ----------------------------------------------
// blocks [0,256):   GEMM1 q_part = xn @ WqT, splitK=4 (Kper=512, 8 K-tiles)
// blocks [256,384): GEMM2 kv_part = mediab @ WkvT, splitK=4 (Kper=256, 4 tiles)
//                   partials -> qbuf..aout ws region (16MB, R4-R6 proven layout)
__global__ __launch_bounds__(512, 2) void gemm12_k(const bf16_t* __restrict__ xn,
                                                   const bf16_t* __restrict__ WqT,
                                                   bf16_t* __restrict__ part,
                                                   const bf16_t* __restrict__ mediab,
                                                   const bf16_t* __restrict__ WkvT,
                                                   bf16_t* __restrict__ kvpart) {
    __shared__ __align__(16) bf16_t lA[2 * 16384];
    int bid = blockIdx.x;
    if (bid < 256)
        gemm_body256<bf16_t>(xn, WqT, part, 8192, 512, 2048, 512, 1.0f, bid, 2, 32, 4, lA);
    else
        gemm_body256<bf16_t>(mediab, WkvT, kvpart, 2048, 1024, 1024, 256, 1.0f, bid - 256, 4, 8, 4, lA);
}

// ---------- GEMM3: out = aout @ WoutT (fp32 out), 256 blocks = 1/CU -----------
__global__ __launch_bounds__(512, 2) void gemm3_k(const bf16_t* __restrict__ aout,
                                                  const bf16_t* __restrict__ WoutT,
                                                  float* __restrict__ out) {
    __shared__ __align__(16) bf16_t lA[2 * 16384];
    gemm_body256<float>(aout, WoutT, out, 8192, 2048, 512, 512, 1.0f, blockIdx.x, 8, 32, 1, lA);
}

// ---------- reduce 4 bf16 split-K slices -> bf16, with scale ------------------
__global__ __launch_bounds__(256) void reduce4_k(const bf16_t* __restrict__ p,
                                                 bf16_t* __restrict__ o,
                                                 size_t n, float scale) {
    size_t i = ((size_t)blockIdx.x * 256 + threadIdx.x) * 8;
    bf16x8 a0 = *(const bf16x8*)(p + i);
    bf16x8 a1 = *(const bf16x8*)(p + n + i);
    bf16x8 a2 = *(const bf16x8*)(p + 2 * n + i);
    bf16x8 a3 = *(const bf16x8*)(p + 3 * n + i);
    bf16x8 r;
#pragma unroll
    for (int u = 0; u < 8; u++)
        r[u] = (bf16_t)(((float)a0[u] + (float)a1[u] + (float)a2[u] + (float)a3[u]) * scale);
    *(bf16x8*)(o + i) = r;
}

// ---------- MFMA bucketed attention, query-chunked grid -----------------------
__global__ __launch_bounds__(256) void attn_mfma_k(const bf16_t* __restrict__ q,
                                                   const bf16_t* __restrict__ kv,
                                                   const int* __restrict__ bstart,
                                                   const int* __restrict__ bcnt,
                                                   bf16_t* __restrict__ aout) {
    __shared__ __align__(16) bf16_t lK[64 * 64];
    __shared__ __align__(16) bf16_t lVt[64 * 64];
    __shared__ __align__(16) bf16_t lP[4][16 * 64];

    int bid = blockIdx.x;
    int bucket = bid >> 6;
    int h = (bid >> 3) & 7;
    int c = bid & 7;
    int n_q = bcnt[bucket];
    int qlo = c << 8;
    if (n_q <= qlo) return;
    int qhi = (n_q < qlo + 256) ? n_q : (qlo + 256);
    int b = bucket >> 3;
    int timg = bucket & 7;
    int row0 = b * T_TXT + bstart[bucket];   // first query row (global)
    size_t krow0 = (size_t)(b * (T_IMG * N_LAT) + timg * N_LAT);

    int tid = threadIdx.x;
    int wid = tid >> 6, lane = tid & 63;
    int quad = lane >> 4, l16 = lane & 15;

    {
        const bf16_t* s0 = kv + (krow0 + 16 * wid + (lane >> 3)) * (2 * INNER) + h * DHEAD + (lane & 7) * 8;
        const bf16_t* s1 = kv + (krow0 + 16 * wid + 8 + (lane >> 3)) * (2 * INNER) + h * DHEAD + (lane & 7) * 8;
        gld_lds16(s0, lK + wid * 1024);
        gld_lds16(s1, lK + wid * 1024 + 512);
    }
    {
        int key = tid & 63, dblk = tid >> 6;
        const bf16_t* vsrc = kv + (krow0 + key) * (2 * INNER) + INNER + h * DHEAD + dblk * 16;
        bf16x8 v0 = *(const bf16x8*)vsrc;
        bf16x8 v1 = *(const bf16x8*)(vsrc + 8);
#pragma unroll
        for (int u = 0; u < 8; u++) {
            lVt[(dblk * 16 + u) * 64 + key]     = v0[u];
            lVt[(dblk * 16 + 8 + u) * 64 + key] = v1[u];
        }
    }
    __syncthreads();

    for (int c0 = qlo + wid * 16; c0 < qhi; c0 += 64) {
        int qi = row0 + c0 + ((c0 + l16 < n_q) ? l16 : 0);   // contiguous rows

        const bf16_t* qrow = q + (size_t)qi * INNER + h * DHEAD + quad * 8;
        bf16x8 qf0 = *(const bf16x8*)qrow;
        bf16x8 qf1 = *(const bf16x8*)(qrow + 32);
        f32x4 s[4];
#pragma unroll
        for (int nt = 0; nt < 4; nt++) s[nt] = (f32x4){0.f, 0.f, 0.f, 0.f};
#pragma unroll
        for (int nt = 0; nt < 4; nt++) {
            bf16x8 kf0 = *(const bf16x8*)(lK + (l16 + 16 * nt) * 64 + quad * 8);
            bf16x8 kf1 = *(const bf16x8*)(lK + (l16 + 16 * nt) * 64 + 32 + quad * 8);
            s[nt] = __builtin_amdgcn_mfma_f32_16x16x32_bf16(qf0, kf0, s[nt], 0, 0, 0);
            s[nt] = __builtin_amdgcn_mfma_f32_16x16x32_bf16(qf1, kf1, s[nt], 0, 0, 0);
        }

        float mr[4];
#pragma unroll
        for (int r = 0; r < 4; r++) {
            float m = fmaxf(fmaxf(s[0][r], s[1][r]), fmaxf(s[2][r], s[3][r]));
#pragma unroll
            for (int off = 8; off >= 1; off >>= 1) m = fmaxf(m, __shfl_xor(m, off));
            mr[r] = m;
        }
        float p[4][4];
#pragma unroll
        for (int nt = 0; nt < 4; nt++)
#pragma unroll
            for (int r = 0; r < 4; r++)
                p[nt][r] = __expf(s[nt][r] - mr[r]);
#pragma unroll
        for (int r = 0; r < 4; r++) {
            float tsum = p[0][r] + p[1][r] + p[2][r] + p[3][r];
#pragma unroll
            for (int off = 8; off >= 1; off >>= 1) tsum += __shfl_xor(tsum, off);
            float inv = 1.0f / tsum;
            p[0][r] *= inv; p[1][r] *= inv; p[2][r] *= inv; p[3][r] *= inv;
        }

        bf16_t* pt = lP[wid];
#pragma unroll
        for (int nt = 0; nt < 4; nt++)
#pragma unroll
            for (int r = 0; r < 4; r++)
                pt[(quad * 4 + r) * 64 + 16 * nt + l16] = (bf16_t)p[nt][r];
        asm volatile("s_waitcnt lgkmcnt(0)" ::: "memory");

        bf16x8 pf0 = *(const bf16x8*)(pt + l16 * 64 + quad * 8);
        bf16x8 pf1 = *(const bf16x8*)(pt + l16 * 64 + 32 + quad * 8);
        f32x4 o[4];
#pragma unroll
        for (int ntd = 0; ntd < 4; ntd++) o[ntd] = (f32x4){0.f, 0.f, 0.f, 0.f};
#pragma unroll
        for (int ntd = 0; ntd < 4; ntd++) {
            bf16x8 vf0 = *(const bf16x8*)(lVt + (l16 + 16 * ntd) * 64 + quad * 8);
            bf16x8 vf1 = *(const bf16x8*)(lVt + (l16 + 16 * ntd) * 64 + 32 + quad * 8);
            o[ntd] = __builtin_amdgcn_mfma_f32_16x16x32_bf16(pf0, vf0, o[ntd], 0, 0, 0);
            o[ntd] = __builtin_amdgcn_mfma_f32_16x16x32_bf16(pf1, vf1, o[ntd], 0, 0, 0);
        }

#pragma unroll
        for (int r = 0; r < 4; r++) {
            int qidx = c0 + quad * 4 + r;
            if (qidx < n_q) {
                bf16_t* op = aout + (size_t)(row0 + qidx) * INNER + h * DHEAD + l16;
#pragma unroll
                for (int ntd = 0; ntd < 4; ntd++)
                    op[16 * ntd] = (bf16_t)o[ntd][r];
            }
        }
    }
}

// ---------- launch ------------------------------------------------------------
extern "C" void kernel_launch(void* const* d_in, const int* in_sizes, int n_in,
                              void* d_out, int out_size, void* d_ws, size_t ws_size,
                              hipStream_t stream) {
    const float* x     = (const float*)d_in[0];
    const float* media = (const float*)d_in[1];
    const void*  locs  = d_in[2];
    const float* gamma = (const float*)d_in[3];
    const float* beta  = (const float*)d_in[4];
    const float* Wq    = (const float*)d_in[5];
    const float* Wkv   = (const float*)d_in[6];
    const float* Wout  = (const float*)d_in[7];
    float* out = (float*)d_out;

    // d_out (64MB fp32) doubles as scratch before GEMM3 overwrites it:
    //   lower 32MB: xn (bf16 LN output, GEMM1's A)
    //   upper 32MB: GEMM1 split-K bf16 partials (4 x 8MB)
    bf16_t* xn   = (bf16_t*)d_out;
    bf16_t* part = (bf16_t*)d_out + (size_t)16 * 1024 * 1024;

    // ws layout: EXACT R4-R6 proven 30MB footprint (R7's 46MB was the crash
    // suspect). GEMM2 splitK partials live in the contiguous qbuf..aout 16MB.
    char* p = (char*)d_ws;
    bf16_t* qbuf   = (bf16_t*)p; p += (size_t)8192 * 512 * 2;    // 8 MB
    bf16_t* aout   = (bf16_t*)p; p += (size_t)8192 * 512 * 2;    // 8 MB
    bf16_t* kvbuf  = (bf16_t*)p; p += (size_t)2048 * 1024 * 2;   // 4 MB
    bf16_t* mediab = (bf16_t*)p; p += (size_t)2048 * 1024 * 2;   // 4 MB
    bf16_t* WqT    = (bf16_t*)p; p += (size_t)512 * 2048 * 2;    // 2 MB
    bf16_t* WkvT   = (bf16_t*)p; p += (size_t)1024 * 1024 * 2;   // 2 MB
    bf16_t* WoutT  = (bf16_t*)p; p += (size_t)2048 * 512 * 2;    // 2 MB
    int*    bstart = (int*)p;    p += 32 * sizeof(int);
    int*    bcnt   = (int*)p;    p += 32 * sizeof(int);

    // fused preamble: weight transposes + media cvt + bucket cumsum
    prep_k<<<4100, 256, 0, stream>>>(Wq, Wkv, Wout, WqT, WkvT, WoutT,
                                     media, mediab, locs, bstart, bcnt);

    ln_k<<<8192, 256, 0, stream>>>(x, gamma, beta, xn);

    // merged GEMM1 (splitK4 -> part) + GEMM2 (splitK4 -> qbuf..aout region)
    gemm12_k<<<384, 512, 0, stream>>>(xn, WqT, part, mediab, WkvT, qbuf);

    // reduce GEMM2 partials first (frees qbuf region), then GEMM1 partials
    reduce4_k<<<1024, 256, 0, stream>>>(qbuf, kvbuf, (size_t)2048 * 1024, 1.0f);
    reduce4_k<<<2048, 256, 0, stream>>>(part, qbuf, (size_t)8192 * 512, 0.125f);

    hipMemsetAsync(aout, 0, (size_t)8192 * 512 * 2, stream);

    attn_mfma_k<<<32 * HEADS * 8, 256, 0, stream>>>(qbuf, kvbuf, bstart, bcnt, aout);

    // GEMM3: out = aout @ Wout (fp32 out), 256 blocks = exactly 1/CU
    gemm3_k<<<256, 512, 0, stream>>>(aout, WoutT, out);
}

// Round 9
// 257.832 us; speedup vs baseline: 1.0744x; 1.0744x over previous
//
#include <hip/hip_runtime.h>
#include <hip/hip_bf16.h>
#include <stdint.h>

typedef __bf16 bf16_t;
typedef __bf16 bf16x8 __attribute__((ext_vector_type(8)));
typedef float f32x4 __attribute__((ext_vector_type(4)));

#define NB      4
#define T_TXT   2048
#define T_IMG   8
#define N_LAT   64
#define DIM     2048
#define DIM_VIS 1024
#define HEADS   8
#define DHEAD   64
#define INNER   512

__device__ __forceinline__ void gld_lds16(const void* g, void* l) {
    __builtin_amdgcn_global_load_lds((const __attribute__((address_space(1))) void*)g,
                                     (__attribute__((address_space(3))) void*)l,
                                     16, 0, 0);
}

// ---------- fused preamble: 3 weight transposes + media cvt + cumsum ----------
// grid = 4100: [0,3072) transpose tiles, [3072,4096) cvt, [4096,4100) cumsum.
// Verified R8 (passed).
__global__ __launch_bounds__(256) void prep_k(const float* __restrict__ Wq,
                                              const float* __restrict__ Wkv,
                                              const float* __restrict__ Wout,
                                              bf16_t* __restrict__ WqT,
                                              bf16_t* __restrict__ WkvT,
                                              bf16_t* __restrict__ WoutT,
                                              const float* __restrict__ media,
                                              bf16_t* __restrict__ mediab,
                                              const void* __restrict__ locs,
                                              int* __restrict__ bstart,
                                              int* __restrict__ bcnt) {
    __shared__ union {
        float tile[32][33];
        struct { int so[4]; int sf[4]; int sc[256]; int sstart[T_IMG]; } cs;
    } sm;
    int bid = blockIdx.x;
    int tid = threadIdx.x;

    if (bid < 3072) {               // ---- transpose+cvt of one 32x32 tile ----
        int which = bid >> 10, tix = bid & 1023;
        const float* in; bf16_t* out; int R, C;
        if (which == 0)      { in = Wq;   out = WqT;   R = 2048; C = 512;  }
        else if (which == 1) { in = Wkv;  out = WkvT;  R = 1024; C = 1024; }
        else                 { in = Wout; out = WoutT; R = 512;  C = 2048; }
        int nbx = C >> 5;
        int bx = tix % nbx, by = tix / nbx;
        int c0 = bx * 32, r0 = by * 32;
        int x = tid & 31, y = tid >> 5;    // 32 x 8
#pragma unroll
        for (int d = 0; d < 4; d++)
            sm.tile[y + d * 8][x] = in[(size_t)(r0 + y + d * 8) * C + c0 + x];
        __syncthreads();
#pragma unroll
        for (int d = 0; d < 4; d++)
            out[(size_t)(c0 + y + d * 8) * R + r0 + x] = (bf16_t)sm.tile[x][y + d * 8];
        return;
    }
    if (bid < 4096) {               // ---- media fp32 -> bf16 ----
        int idx = ((bid - 3072) * 256 + tid) * 8;
        f32x4 a = *(const f32x4*)(media + idx);
        f32x4 b = *(const f32x4*)(media + idx + 4);
        bf16x8 o;
#pragma unroll
        for (int i = 0; i < 4; i++) { o[i] = (bf16_t)a[i]; o[i + 4] = (bf16_t)b[i]; }
        *(bf16x8*)(mediab + idx) = o;
        return;
    }
    // ---- cumsum + contiguous bucket ranges (NO atomics), b = bid-4096 -------
    {
        int b = bid - 4096, t = tid;
        const unsigned* up = (const unsigned*)locs;
        const int* ip = (const int*)locs;
        const unsigned char* bp = (const unsigned char*)locs;
        const float* fp = (const float*)locs;

        int other = 0, nf = 0;
#pragma unroll
        for (int i = 0; i < 8; i++) {
            unsigned wv = up[t * 8 + i];
            nf    += (wv == 0x3F800000u);
            other += (wv != 0u && wv != 1u && wv != 0x3F800000u);
        }
#pragma unroll
        for (int off = 32; off > 0; off >>= 1) { other += __shfl_xor(other, off); nf += __shfl_xor(nf, off); }
        int wid = t >> 6, lane = t & 63;
        if (lane == 0) { sm.cs.so[wid] = other; sm.cs.sf[wid] = nf; }
        __syncthreads();
        other = sm.cs.so[0] + sm.cs.so[1] + sm.cs.so[2] + sm.cs.so[3];
        nf    = sm.cs.sf[0] + sm.cs.sf[1] + sm.cs.sf[2] + sm.cs.sf[3];
        int mode = (other > 0) ? 0 : ((nf > 0) ? 2 : 1);   // 0=u8, 1=i32, 2=f32

        int v[8];
        int s = 0;
#pragma unroll
        for (int i = 0; i < 8; i++) {
            int idx = b * T_TXT + t * 8 + i;
            int xv;
            if (mode == 1)      xv = ip[idx];
            else if (mode == 0) xv = (int)bp[idx];
            else                xv = (fp[idx] != 0.f) ? 1 : 0;
            v[i] = xv;
            s += xv;
        }
        if (t < T_IMG) sm.cs.sstart[t] = T_TXT;   // sentinel
        sm.cs.sc[t] = s;
        __syncthreads();
        for (int off = 1; off < 256; off <<= 1) {
            int add = (t >= off) ? sm.cs.sc[t - off] : 0;
            __syncthreads();
            sm.cs.sc[t] += add;
            __syncthreads();
        }
        int run = sm.cs.sc[t] - s;   // exclusive prefix of this thread's chunk
#pragma unroll
        for (int i = 0; i < 8; i++) {
            run += v[i];
            if (v[i] && run <= T_IMG) sm.cs.sstart[run - 1] = t * 8 + i;  // unique writer
        }
        __syncthreads();
        if (t < T_IMG) {
            int st = sm.cs.sstart[t];
            int nx = (t + 1 < T_IMG) ? sm.cs.sstart[t + 1] : T_TXT;
            bstart[b * T_IMG + t] = st;
            bcnt[b * T_IMG + t]   = nx - st;   // 0 for empty tail buckets
        }
    }
}

// ---------- LayerNorm: fp32 in, bf16 out; one block per row of 2048 -----------
__global__ __launch_bounds__(256) void ln_k(const float* __restrict__ x,
                                            const float* __restrict__ gamma,
                                            const float* __restrict__ beta,
                                            bf16_t* __restrict__ xn) {
    int row = blockIdx.x;
    int t = threadIdx.x;
    const float* xp = x + (size_t)row * DIM + t * 8;
    f32x4 v0 = *(const f32x4*)xp;
    f32x4 v1 = *(const f32x4*)(xp + 4);
    float f[8];
    float s = 0.f, ss = 0.f;
#pragma unroll
    for (int i = 0; i < 4; i++) { f[i] = v0[i]; f[i + 4] = v1[i]; }
#pragma unroll
    for (int i = 0; i < 8; i++) { s += f[i]; ss += f[i] * f[i]; }
#pragma unroll
    for (int off = 32; off > 0; off >>= 1) { s += __shfl_xor(s, off); ss += __shfl_xor(ss, off); }
    __shared__ float sbuf[4], sbuf2[4];
    int wid = t >> 6, lane = t & 63;
    if (lane == 0) { sbuf[wid] = s; sbuf2[wid] = ss; }
    __syncthreads();
    s  = sbuf[0] + sbuf[1] + sbuf[2] + sbuf[3];
    ss = sbuf2[0] + sbuf2[1] + sbuf2[2] + sbuf2[3];
    float mu  = s * (1.0f / DIM);
    float var = ss * (1.0f / DIM) - mu * mu;
    float rs  = rsqrtf(var + 1e-5f);
    f32x4 g0 = *(const f32x4*)(gamma + t * 8);
    f32x4 g1 = *(const f32x4*)(gamma + t * 8 + 4);
    f32x4 b0 = *(const f32x4*)(beta + t * 8);
    f32x4 b1 = *(const f32x4*)(beta + t * 8 + 4);
    bf16x8 o;
#pragma unroll
    for (int i = 0; i < 4; i++) {
        o[i]     = (bf16_t)((f[i]     - mu) * rs * g0[i] + b0[i]);
        o[i + 4] = (bf16_t)((f[i + 4] - mu) * rs * g1[i] + b1[i]);
    }
    *(bf16x8*)(xn + (size_t)row * DIM + t * 8) = o;
}

// ---------- GEMM body: 256x256, 8 waves, BK=32, depth-4 counted pipeline ------
// R5's exact structure (best measured: 44.5 us; R8's B-in-reg regressed to 58).
// 4 LDS buffers (128 KB), prologue stages tiles 0-2; each K-step waits
// vmcnt(8) (tile t, issued 3 phases earlier), one raw s_barrier, ds_read
// frags, issue stage(t+3), 32 setprio-wrapped MFMAs. Tail peels vmcnt(4)/(0).
// Chunk-major 16x32 sections (R2-R6: SQ_LDS_BANK_CONFLICT = 0).
template <typename OT>
__device__ __forceinline__ void gemm_body256(const bf16_t* __restrict__ A,
                                             const bf16_t* __restrict__ Bt,
                                             OT* __restrict__ C,
                                             int M, int N, int K, int Kper,
                                             float scale, int bid,
                                             int gx, int gy, int gz,
                                             bf16_t* lA, bf16_t* lB) {
    int tid = threadIdx.x;
    int w = tid >> 6, lane = tid & 63;
    int wm = w >> 2, wn = w & 3;

    // bijective XCD swizzle (nwg % 8 == 0 for all dispatches)
    int nwg = gx * gy * gz;
    int cpx = nwg >> 3;
    int nid = (bid & 7) * cpx + (bid >> 3);
    int tpy = gx * gz;
    int by = nid / tpy;
    int rr = nid - by * tpy;
    int bz = rr / gx;
    int bx = rr - bz * gx;

    int bm0 = by * 256, bn0 = bx * 256;
    int kbase = bz * Kper;
    int q = lane >> 4, l16 = lane & 15;

    // staging sources: section = 16 rows x 32 K-cols, lane -> (row=l16, chunk=q)
    const bf16_t* pA0 = A  + (size_t)(bm0 + w * 32      + l16) * K + kbase + q * 8;
    const bf16_t* pA1 = A  + (size_t)(bm0 + w * 32 + 16 + l16) * K + kbase + q * 8;
    const bf16_t* pB0 = Bt + (size_t)(bn0 + w * 32      + l16) * K + kbase + q * 8;
    const bf16_t* pB1 = Bt + (size_t)(bn0 + w * 32 + 16 + l16) * K + kbase + q * 8;

    f32x4 acc[8][4];
#pragma unroll
    for (int i = 0; i < 8; i++)
#pragma unroll
        for (int j = 0; j < 4; j++)
            acc[i][j] = (f32x4){0.f, 0.f, 0.f, 0.f};

    auto stage = [&](int t) {
        int buf = t & 3;
        int k0 = t << 5;
        gld_lds16(pA0 + k0, lA + buf * 8192 + (w * 2)     * 512);
        gld_lds16(pA1 + k0, lA + buf * 8192 + (w * 2 + 1) * 512);
        gld_lds16(pB0 + k0, lB + buf * 8192 + (w * 2)     * 512);
        gld_lds16(pB1 + k0, lB + buf * 8192 + (w * 2 + 1) * 512);
    };
    auto compute = [&](int t, bool dostage) {
        int buf = t & 3;
        bf16x8 af[8], bfr[4];
#pragma unroll
        for (int mt = 0; mt < 8; mt++)
            af[mt] = *(const bf16x8*)(lA + buf * 8192 + (wm * 8 + mt) * 512 + q * 128 + l16 * 8);
#pragma unroll
        for (int nt = 0; nt < 4; nt++)
            bfr[nt] = *(const bf16x8*)(lB + buf * 8192 + (wn * 4 + nt) * 512 + q * 128 + l16 * 8);
        if (dostage) stage(t + 3);
        __builtin_amdgcn_s_setprio(1);
#pragma unroll
        for (int mt = 0; mt < 8; mt++)
#pragma unroll
            for (int nt = 0; nt < 4; nt++)
                acc[mt][nt] = __builtin_amdgcn_mfma_f32_16x16x32_bf16(af[mt], bfr[nt], acc[mt][nt], 0, 0, 0);
        __builtin_amdgcn_s_setprio(0);
    };

    int nsteps = Kper >> 5;        // 16 (GEMM1/3) or 32 (GEMM2)
    stage(0); stage(1); stage(2);  // 12 loads/wave in flight
    for (int t = 0; t < nsteps - 2; t++) {
        asm volatile("s_waitcnt vmcnt(8)" ::: "memory");   // tile t landed (own loads)
        __builtin_amdgcn_s_barrier();                      // everyone's tile t landed
        __builtin_amdgcn_sched_barrier(0);
        compute(t, t + 3 < nsteps);
    }
    asm volatile("s_waitcnt vmcnt(4)" ::: "memory");
    __builtin_amdgcn_s_barrier();
    __builtin_amdgcn_sched_barrier(0);
    compute(nsteps - 2, false);
    asm volatile("s_waitcnt vmcnt(0)" ::: "memory");
    __builtin_amdgcn_s_barrier();
    __builtin_amdgcn_sched_barrier(0);
    compute(nsteps - 1, false);

    OT* Cz = C + (size_t)bz * M * N;
#pragma unroll
    for (int mt = 0; mt < 8; mt++)
#pragma unroll
        for (int nt = 0; nt < 4; nt++)
#pragma unroll
            for (int r = 0; r < 4; r++) {
                int row = bm0 + wm * 128 + mt * 16 + q * 4 + r;
                int col = bn0 + wn * 64 + nt * 16 + l16;
                Cz[(size_t)row * N + col] = (OT)(acc[mt][nt][r] * scale);
            }
}

// ---------- merged GEMM2 (direct kvbuf, FIRST) + GEMM1 (splitK4) --------------
// blocks [0,32):   GEMM2 kvbuf = mediab @ WkvT, UNSPLIT (Kper=1024, 32 steps)
//                  -> no kv partials, no kv reduce
// blocks [32,288): GEMM1 q_part = xn @ WqT, splitK=4 (Kper=512, 16 steps)
__global__ __launch_bounds__(512, 2) void gemm12_k(const bf16_t* __restrict__ xn,
                                                   const bf16_t* __restrict__ WqT,
                                                   bf16_t* __restrict__ part,
                                                   const bf16_t* __restrict__ mediab,
                                                   const bf16_t* __restrict__ WkvT,
                                                   bf16_t* __restrict__ kvbuf) {
    __shared__ __align__(16) bf16_t lA[4 * 8192];
    __shared__ __align__(16) bf16_t lB[4 * 8192];
    int bid = blockIdx.x;
    if (bid < 32)
        gemm_body256<bf16_t>(mediab, WkvT, kvbuf, 2048, 1024, 1024, 1024, 1.0f, bid, 4, 8, 1, lA, lB);
    else
        gemm_body256<bf16_t>(xn, WqT, part, 8192, 512, 2048, 512, 1.0f, bid - 32, 2, 32, 4, lA, lB);
}

// ---------- GEMM3: out = aout @ WoutT (fp32 out), 256 blocks = 1/CU -----------
__global__ __launch_bounds__(512, 2) void gemm3_k(const bf16_t* __restrict__ aout,
                                                  const bf16_t* __restrict__ WoutT,
                                                  float* __restrict__ out) {
    __shared__ __align__(16) bf16_t lA[4 * 8192];
    __shared__ __align__(16) bf16_t lB[4 * 8192];
    gemm_body256<float>(aout, WoutT, out, 8192, 2048, 512, 512, 1.0f, blockIdx.x, 8, 32, 1, lA, lB);
}

// ---------- fused: q-reduce (4 splitK slices, x0.125) + aout zeroing ----------
// 2048 blocks x 256 thr x 8 elems = exactly 8192*512. Replaces reduce4_k +
// hipMemsetAsync (aout slice i zeroed by the same thread that writes qbuf[i]).
__global__ __launch_bounds__(256) void reduce4_zero_k(const bf16_t* __restrict__ p,
                                                      bf16_t* __restrict__ qbuf,
                                                      bf16_t* __restrict__ aout) {
    size_t n = (size_t)8192 * 512;
    size_t i = ((size_t)blockIdx.x * 256 + threadIdx.x) * 8;
    bf16x8 a0 = *(const bf16x8*)(p + i);
    bf16x8 a1 = *(const bf16x8*)(p + n + i);
    bf16x8 a2 = *(const bf16x8*)(p + 2 * n + i);
    bf16x8 a3 = *(const bf16x8*)(p + 3 * n + i);
    bf16x8 r, z;
#pragma unroll
    for (int u = 0; u < 8; u++) {
        r[u] = (bf16_t)(((float)a0[u] + (float)a1[u] + (float)a2[u] + (float)a3[u]) * 0.125f);
        z[u] = (bf16_t)0.f;
    }
    *(bf16x8*)(qbuf + i) = r;
    *(bf16x8*)(aout + i) = z;
}

// ---------- MFMA bucketed attention, query-chunked grid -----------------------
__global__ __launch_bounds__(256) void attn_mfma_k(const bf16_t* __restrict__ q,
                                                   const bf16_t* __restrict__ kv,
                                                   const int* __restrict__ bstart,
                                                   const int* __restrict__ bcnt,
                                                   bf16_t* __restrict__ aout) {
    __shared__ __align__(16) bf16_t lK[64 * 64];
    __shared__ __align__(16) bf16_t lVt[64 * 64];
    __shared__ __align__(16) bf16_t lP[4][16 * 64];

    int bid = blockIdx.x;
    int bucket = bid >> 6;
    int h = (bid >> 3) & 7;
    int c = bid & 7;
    int n_q = bcnt[bucket];
    int qlo = c << 8;
    if (n_q <= qlo) return;
    int qhi = (n_q < qlo + 256) ? n_q : (qlo + 256);
    int b = bucket >> 3;
    int timg = bucket & 7;
    int row0 = b * T_TXT + bstart[bucket];   // first query row (global)
    size_t krow0 = (size_t)(b * (T_IMG * N_LAT) + timg * N_LAT);

    int tid = threadIdx.x;
    int wid = tid >> 6, lane = tid & 63;
    int quad = lane >> 4, l16 = lane & 15;

    {
        const bf16_t* s0 = kv + (krow0 + 16 * wid + (lane >> 3)) * (2 * INNER) + h * DHEAD + (lane & 7) * 8;
        const bf16_t* s1 = kv + (krow0 + 16 * wid + 8 + (lane >> 3)) * (2 * INNER) + h * DHEAD + (lane & 7) * 8;
        gld_lds16(s0, lK + wid * 1024);
        gld_lds16(s1, lK + wid * 1024 + 512);
    }
    {
        int key = tid & 63, dblk = tid >> 6;
        const bf16_t* vsrc = kv + (krow0 + key) * (2 * INNER) + INNER + h * DHEAD + dblk * 16;
        bf16x8 v0 = *(const bf16x8*)vsrc;
        bf16x8 v1 = *(const bf16x8*)(vsrc + 8);
#pragma unroll
        for (int u = 0; u < 8; u++) {
            lVt[(dblk * 16 + u) * 64 + key]     = v0[u];
            lVt[(dblk * 16 + 8 + u) * 64 + key] = v1[u];
        }
    }
    __syncthreads();

    for (int c0 = qlo + wid * 16; c0 < qhi; c0 += 64) {
        int qi = row0 + c0 + ((c0 + l16 < n_q) ? l16 : 0);   // contiguous rows

        const bf16_t* qrow = q + (size_t)qi * INNER + h * DHEAD + quad * 8;
        bf16x8 qf0 = *(const bf16x8*)qrow;
        bf16x8 qf1 = *(const bf16x8*)(qrow + 32);
        f32x4 s[4];
#pragma unroll
        for (int nt = 0; nt < 4; nt++) s[nt] = (f32x4){0.f, 0.f, 0.f, 0.f};
#pragma unroll
        for (int nt = 0; nt < 4; nt++) {
            bf16x8 kf0 = *(const bf16x8*)(lK + (l16 + 16 * nt) * 64 + quad * 8);
            bf16x8 kf1 = *(const bf16x8*)(lK + (l16 + 16 * nt) * 64 + 32 + quad * 8);
            s[nt] = __builtin_amdgcn_mfma_f32_16x16x32_bf16(qf0, kf0, s[nt], 0, 0, 0);
            s[nt] = __builtin_amdgcn_mfma_f32_16x16x32_bf16(qf1, kf1, s[nt], 0, 0, 0);
        }

        float mr[4];
#pragma unroll
        for (int r = 0; r < 4; r++) {
            float m = fmaxf(fmaxf(s[0][r], s[1][r]), fmaxf(s[2][r], s[3][r]));
#pragma unroll
            for (int off = 8; off >= 1; off >>= 1) m = fmaxf(m, __shfl_xor(m, off));
            mr[r] = m;
        }
        float p[4][4];
#pragma unroll
        for (int nt = 0; nt < 4; nt++)
#pragma unroll
            for (int r = 0; r < 4; r++)
                p[nt][r] = __expf(s[nt][r] - mr[r]);
#pragma unroll
        for (int r = 0; r < 4; r++) {
            float tsum = p[0][r] + p[1][r] + p[2][r] + p[3][r];
#pragma unroll
            for (int off = 8; off >= 1; off >>= 1) tsum += __shfl_xor(tsum, off);
            float inv = 1.0f / tsum;
            p[0][r] *= inv; p[1][r] *= inv; p[2][r] *= inv; p[3][r] *= inv;
        }

        bf16_t* pt = lP[wid];
#pragma unroll
        for (int nt = 0; nt < 4; nt++)
#pragma unroll
            for (int r = 0; r < 4; r++)
                pt[(quad * 4 + r) * 64 + 16 * nt + l16] = (bf16_t)p[nt][r];
        asm volatile("s_waitcnt lgkmcnt(0)" ::: "memory");

        bf16x8 pf0 = *(const bf16x8*)(pt + l16 * 64 + quad * 8);
        bf16x8 pf1 = *(const bf16x8*)(pt + l16 * 64 + 32 + quad * 8);
        f32x4 o[4];
#pragma unroll
        for (int ntd = 0; ntd < 4; ntd++) o[ntd] = (f32x4){0.f, 0.f, 0.f, 0.f};
#pragma unroll
        for (int ntd = 0; ntd < 4; ntd++) {
            bf16x8 vf0 = *(const bf16x8*)(lVt + (l16 + 16 * ntd) * 64 + quad * 8);
            bf16x8 vf1 = *(const bf16x8*)(lVt + (l16 + 16 * ntd) * 64 + 32 + quad * 8);
            o[ntd] = __builtin_amdgcn_mfma_f32_16x16x32_bf16(pf0, vf0, o[ntd], 0, 0, 0);
            o[ntd] = __builtin_amdgcn_mfma_f32_16x16x32_bf16(pf1, vf1, o[ntd], 0, 0, 0);
        }

#pragma unroll
        for (int r = 0; r < 4; r++) {
            int qidx = c0 + quad * 4 + r;
            if (qidx < n_q) {
                bf16_t* op = aout + (size_t)(row0 + qidx) * INNER + h * DHEAD + l16;
#pragma unroll
                for (int ntd = 0; ntd < 4; ntd++)
                    op[16 * ntd] = (bf16_t)o[ntd][r];
            }
        }
    }
}

// ---------- launch ------------------------------------------------------------
extern "C" void kernel_launch(void* const* d_in, const int* in_sizes, int n_in,
                              void* d_out, int out_size, void* d_ws, size_t ws_size,
                              hipStream_t stream) {
    const float* x     = (const float*)d_in[0];
    const float* media = (const float*)d_in[1];
    const void*  locs  = d_in[2];
    const float* gamma = (const float*)d_in[3];
    const float* beta  = (const float*)d_in[4];
    const float* Wq    = (const float*)d_in[5];
    const float* Wkv   = (const float*)d_in[6];
    const float* Wout  = (const float*)d_in[7];
    float* out = (float*)d_out;

    // d_out (64MB fp32) doubles as scratch before GEMM3 overwrites it:
    //   lower 32MB: xn (bf16 LN output, GEMM1's A)
    //   upper 32MB: GEMM1 split-K bf16 partials (4 x 8MB)
    bf16_t* xn   = (bf16_t*)d_out;
    bf16_t* part = (bf16_t*)d_out + (size_t)16 * 1024 * 1024;

    // ws layout: EXACT R4-R6 proven 30MB footprint.
    char* p = (char*)d_ws;
    bf16_t* qbuf   = (bf16_t*)p; p += (size_t)8192 * 512 * 2;    // 8 MB
    bf16_t* aout   = (bf16_t*)p; p += (size_t)8192 * 512 * 2;    // 8 MB
    bf16_t* kvbuf  = (bf16_t*)p; p += (size_t)2048 * 1024 * 2;   // 4 MB
    bf16_t* mediab = (bf16_t*)p; p += (size_t)2048 * 1024 * 2;   // 4 MB
    bf16_t* WqT    = (bf16_t*)p; p += (size_t)512 * 2048 * 2;    // 2 MB
    bf16_t* WkvT   = (bf16_t*)p; p += (size_t)1024 * 1024 * 2;   // 2 MB
    bf16_t* WoutT  = (bf16_t*)p; p += (size_t)2048 * 512 * 2;    // 2 MB
    int*    bstart = (int*)p;    p += 32 * sizeof(int);
    int*    bcnt   = (int*)p;    p += 32 * sizeof(int);

    // fused preamble: weight transposes + media cvt + bucket cumsum
    prep_k<<<4100, 256, 0, stream>>>(Wq, Wkv, Wout, WqT, WkvT, WoutT,
                                     media, mediab, locs, bstart, bcnt);

    ln_k<<<8192, 256, 0, stream>>>(x, gamma, beta, xn);

    // merged GEMM2 (unsplit -> kvbuf direct) + GEMM1 (splitK4 -> part)
    gemm12_k<<<288, 512, 0, stream>>>(xn, WqT, part, mediab, WkvT, kvbuf);

    // fused: q-reduce + aout zeroing (replaces reduce4 + memset)
    reduce4_zero_k<<<2048, 256, 0, stream>>>(part, qbuf, aout);

    attn_mfma_k<<<32 * HEADS * 8, 256, 0, stream>>>(qbuf, kvbuf, bstart, bcnt, aout);

    // GEMM3: out = aout @ Wout (fp32 out), 256 blocks = exactly 1/CU
    gemm3_k<<<256, 512, 0, stream>>>(aout, WoutT, out);
}